// Round 10
// baseline (120.823 us; speedup 1.0000x reference)
//
#include <hip/hip_runtime.h>

// Problem constants (fixed by setup_inputs)
#define B_   16
#define T_   2048
#define F_   64
#define A_   48
#define TOK  64              // tokens per block (4 waves x 16 tokens)
#define WSTR 68              // fp32 window row stride (floats)
#define HWS  72              // f16 window row stride (halves): 144B, 16B-aligned rows
#define SSTR 49              // score row stride (floats)
#define NWIN 111             // window rows: t0-48 .. t0+62

typedef __attribute__((ext_vector_type(8))) _Float16 half8;  // 16x16x32 A/B frag
typedef __attribute__((ext_vector_type(4))) _Float16 half4;
typedef __attribute__((ext_vector_type(2))) _Float16 h2;
typedef __attribute__((ext_vector_type(4))) float    f32x4;  // 16x16x32 C/D frag

#define LOG2E 1.4426950408889634f

// Hardware-trans sigmoid (R3+R7: v_exp_f32+v_rcp_f32 beat any replacement).
// W pre-scaled by -log2e: sigma(x) = rcp(1 + 2^c).
__device__ __forceinline__ float sigp(float c) {
    return __builtin_amdgcn_rcpf(1.0f + __builtin_amdgcn_exp2f(c));
}
__device__ __forceinline__ h2 pk2(float a, float b) {
    return __builtin_bit_cast(h2, __builtin_amdgcn_cvt_pkrtz(a, b));
}
// K=32 frag from two C/D frags: elems 0..3 = sigma(a), 4..7 = sigma(b).
__device__ __forceinline__ half8 sig8(const f32x4& a, const f32x4& b) {
    h2 p0 = pk2(sigp(a[0]), sigp(a[1])), p1 = pk2(sigp(a[2]), sigp(a[3]));
    h2 p2 = pk2(sigp(b[0]), sigp(b[1])), p3 = pk2(sigp(b[2]), sigp(b[3]));
    half8 h;
    h[0]=p0[0]; h[1]=p0[1]; h[2]=p1[0]; h[3]=p1[1];
    h[4]=p2[0]; h[5]=p2[1]; h[6]=p3[0]; h[7]=p3[1];
    return h;
}

// Slot->semantic-feature map for all K=32 operands (layout-cancelling):
// F(kt,q,j) = 32kt + 16*(j>>2) + 4q + (j&3). A and B share the hardware
// (lane-group, elem)->k map, so packing BOTH sides by F makes the contraction
// sum over semantic features regardless of the actual hardware k layout.
// Compose identity: C/D slot (mo, reg, q) = feature 16mo+4q+reg goes to
// B slot (kt=mo>>1, j=4*(mo&1)+reg)  ->  hb[kt] = sig8(c[2kt], c[2kt+1]).

// 4x2 MFMA sweep: c[mo] = A[mo][:] x hb (K=64 via 2 chained 16x16x32)
__device__ __forceinline__ void gemm42(const half8 (&aW)[4][2], const half8 (&hb)[2], f32x4 (&c)[4]) {
#pragma unroll
    for (int mo = 0; mo < 4; ++mo) {
        f32x4 z = {0.f, 0.f, 0.f, 0.f};
#pragma unroll
        for (int kt = 0; kt < 2; ++kt)
            z = __builtin_amdgcn_mfma_f32_16x16x32_f16(aW[mo][kt], hb[kt], z, 0, 0, 0);
        c[mo] = z;
    }
}

// Same 58.8 KB Smem as the 73.4us baseline. sWinH columns are PERMUTED
// (position p(f): chunk bits [b3 b2 b1 b0] -> [b3 b1 b0 b2]) so a b128 read
// at column kt*32+q*8 yields elems j holding feature F(kt,q,j).
struct Smem {
    float    sWin[NWIN * WSTR];    // 30.2 KB fp32 window, natural order (epilogue)
    _Float16 sWinH[NWIN * HWS];    // 16.0 KB f16 window, permuted columns (score B)
    float    sSc[TOK * SSTR];      // 12.5 KB scores
};

// FIRST = block contains tokens 0..63 (needs clamping + validity masks).
template<bool FIRST>
__device__ __forceinline__ void run_block(Smem& sm, int b, int t0,
                                          const float* __restrict__ he,
                                          const float* __restrict__ W1,
                                          const float* __restrict__ W2,
                                          float* __restrict__ out)
{
    const int tid = threadIdx.x;
    const float* __restrict__ heB = he + (size_t)b * T_ * F_;

    // ---- stage window rows: fp32 natural + f16 permuted. g<0 rows never read.
    for (int i = tid; i < NWIN * 16; i += 256) {
        int row = i >> 4, ch = i & 15, c4 = ch * 4;
        int g = t0 - 48 + row;
        if (!FIRST || g >= 0) {
            float4 v = *(const float4*)(heB + (size_t)g * F_ + c4);
            *(float4*)(&sm.sWin[row * WSTR + c4]) = v;
            int cp = ((ch >> 3) << 3) | ((ch & 3) << 1) | ((ch >> 2) & 1);
            half4 h; h[0] = (_Float16)v.x; h[1] = (_Float16)v.y;
                     h[2] = (_Float16)v.z; h[3] = (_Float16)v.w;
            *(half4*)(&sm.sWinH[row * HWS + cp * 4]) = h;
        }
    }

    const int lane = tid & 63;
    const int wv   = tid >> 6;          // wave owns tokens wv*16 .. wv*16+15
    const int quad = lane >> 4;
    const int ml   = lane & 15;
    const int tw0  = wv * 16;
    const int tg   = t0 + tw0 + ml;     // this lane's token
    const int L    = min(A_, max(tg, 1));

    // ---- A-operands: A[mo][kt] elem j = -log2e * W[F(kt,q,j)][16mo+ml]
    half8 aW1[4][2], aW2[4][2];
    for (int mo = 0; mo < 4; ++mo)
        for (int kt = 0; kt < 2; ++kt) {
            half8 f1, f2;
#pragma unroll
            for (int j = 0; j < 8; ++j) {
                int fk = kt * 32 + ((j >> 2) << 4) + quad * 4 + (j & 3);
                f1[j] = (_Float16)(-LOG2E * W1[fk * F_ + mo * 16 + ml]);
                f2[j] = (_Float16)(-LOG2E * W2[fk * F_ + mo * 16 + ml]);
            }
            aW1[mo][kt] = f1; aW2[mo][kt] = f2;
        }

    // ---- initial H B-frags: hb[kt][j] = he[tg][F(kt,q,j)]
    half8 hb[2];
#pragma unroll
    for (int kt = 0; kt < 2; ++kt) {
        float4 vlo = *(const float4*)(heB + (size_t)tg * F_ + kt * 32 + quad * 4);
        float4 vhi = *(const float4*)(heB + (size_t)tg * F_ + kt * 32 + 16 + quad * 4);
        half8 h;
        h[0] = (_Float16)vlo.x; h[1] = (_Float16)vlo.y;
        h[2] = (_Float16)vlo.z; h[3] = (_Float16)vlo.w;
        h[4] = (_Float16)vhi.x; h[5] = (_Float16)vhi.y;
        h[6] = (_Float16)vhi.z; h[7] = (_Float16)vhi.w;
        hb[kt] = h;
    }

    // ---- prologue GEMM1 (register work overlaps the staging barrier)
    f32x4 c1[4];
    gemm42(aW1, hb, c1);

    __syncthreads();

    // ---- R10: anti-phase stagger. The 2 waves co-resident on a SIMD are
    // trans-pipe-bound (64 trans/step in two 512-cyc bursts separated by
    // MFMA-latency gaps). Starting in lockstep they collide on the trans
    // unit and idle in the gaps together (measured 61% util = the in-phase
    // fixed point). Delaying half the waves ~half a step moves them to the
    // anti-phase fixed point (gap of one filled by burst of the other).
    // Parity (blockIdx ^ wv) covers both plausible SIMD pairings: same-wv
    // of adjacent blocks, and adjacent-wv within a block. One-time cost
    // ~1.4k cyc of 160k. Dependent sigp chain, kept alive via asm sink.
    if ((blockIdx.x ^ wv) & 1) {
        float x = c1[0][0];
#pragma unroll 1
        for (int d = 0; d < 26; ++d) x = sigp(x + 0.125f);
        asm volatile("" :: "v"(x));
    }

    // Diag owner (C/D row = quad*4+reg, col = ml): same as 16x16x16.
    const bool amDiag = (quad == (ml >> 2));
    const bool s0 = (ml & 3) == 0, s1 = (ml & 3) == 1, s2 = (ml & 3) == 2;
    float* scp = &sm.sSc[(tw0 + ml) * SSTR];

    // f16 window base (permuted cols): row for step a is tw0+ml+a; this lane
    // reads 16B at column quad*8 (+32 for kt=1). Rows are 16B-aligned (144B).
    const _Float16* __restrict__ wbase = &sm.sWinH[(tw0 + ml) * HWS + quad * 8];

    auto wp_for = [&](int a2) -> const _Float16* {
        if (FIRST) {
            int j = tg - L + a2; if (j < 0) j = 0;
            return &sm.sWinH[(j + 48) * HWS + quad * 8];
        }
        return wbase + a2 * HWS;
    };

    half8 g0, g1;
    {
        const _Float16* wp = wp_for(0);
        g0 = *(const half8*)(wp);
        g1 = *(const half8*)(wp + 32);
    }

    // ---- 48-step recurrence (R1 pipeline shape, 18 MFMA/step)
#pragma unroll 2
    for (int a = 0; a < A_; ++a) {
        // H_new = sigmoid(c1) -> K=32 B-frags (shuffle-free compose)
        hb[0] = sig8(c1[0], c1[1]);
        hb[1] = sig8(c1[2], c1[3]);

        // GEMM2 (this step) + GEMM1 (next step)
        f32x4 c2[4];
        gemm42(aW2, hb, c2);
        gemm42(aW1, hb, c1);

        // prefetch next step's gathered rows
        half8 n0, n1;
        {
            int an = (a + 1 < A_) ? a + 1 : A_ - 1;
            const _Float16* wp = wp_for(an);
            n0 = *(const half8*)(wp);
            n1 = *(const half8*)(wp + 32);
        }

        // Y -> K=32 A-frags (same compose identity)
        half8 y0 = sig8(c2[0], c2[1]);
        half8 y1 = sig8(c2[2], c2[3]);

        // score S = Y . G^T via 2 chained 16x16x32; need only the diagonal
        f32x4 zs = {0.f, 0.f, 0.f, 0.f};
        zs = __builtin_amdgcn_mfma_f32_16x16x32_f16(y0, g0, zs, 0, 0, 0);
        zs = __builtin_amdgcn_mfma_f32_16x16x32_f16(y1, g1, zs, 0, 0, 0);
        float val = s0 ? zs[0] : (s1 ? zs[1] : (s2 ? zs[2] : zs[3]));
        if (FIRST) val = (a < L) ? val : -1e9f;
        if (amDiag) scp[a] = val;

        g0 = n0; g1 = n1;
    }
    __syncthreads();

    // ---- softmax over a (48): 4 lanes per token, 12 scores each
    {
        int r = tid >> 2, s = tid & 3;
        float sc[12];
#pragma unroll
        for (int i = 0; i < 12; ++i) sc[i] = sm.sSc[r * SSTR + i * 4 + s];
        float m = sc[0];
#pragma unroll
        for (int i = 1; i < 12; ++i) m = fmaxf(m, sc[i]);
        m = fmaxf(m, __shfl_xor(m, 1));
        m = fmaxf(m, __shfl_xor(m, 2));
        float e[12]; float sum = 0.f;
#pragma unroll
        for (int i = 0; i < 12; ++i) { e[i] = __expf(sc[i] - m); sum += e[i]; }
        sum += __shfl_xor(sum, 1);
        sum += __shfl_xor(sum, 2);
        float inv = __builtin_amdgcn_rcpf(sum);
#pragma unroll
        for (int i = 0; i < 12; ++i) sm.sSc[r * SSTR + i * 4 + s] = e[i] * inv;
    }
    __syncthreads();

    // ---- ctx: 4 lanes per token, 16 features each (fp32 window, natural order)
    {
        int r = tid >> 2, fc = (tid & 3) * 16;
        int tgr = t0 + r;
        int Lr = min(A_, max(tgr, 1));
        float acc[16];
#pragma unroll
        for (int q = 0; q < 16; ++q) acc[q] = 0.f;
        for (int a = 0; a < A_; ++a) {
            float wgt = sm.sSc[r * SSTR + a];
            int j = tgr - Lr + a;
            if (FIRST) { if (j < 0) j = 0; }
            const float* wp = &sm.sWin[(j - t0 + 48) * WSTR + fc];
#pragma unroll
            for (int q = 0; q < 4; ++q) {
                float4 g = *(const float4*)(wp + q * 4);
                acc[q*4+0] += wgt * g.x; acc[q*4+1] += wgt * g.y;
                acc[q*4+2] += wgt * g.z; acc[q*4+3] += wgt * g.w;
            }
        }
        float* op = out + ((size_t)b * T_ + tgr) * F_ + fc;
#pragma unroll
        for (int q = 0; q < 4; ++q)
            *(float4*)(op + q * 4) = make_float4(acc[q*4], acc[q*4+1], acc[q*4+2], acc[q*4+3]);
    }
}

__global__ __launch_bounds__(256)
void ContextBlock_kernel(const float* __restrict__ he, const float* __restrict__ W1,
                         const float* __restrict__ W2, float* __restrict__ out)
{
    __shared__ Smem sm;                   // single 58.8 KB allocation, shared by both paths
    const int blk = blockIdx.x;
    if (blk < B_ * 31) {                  // 496 fast blocks: t0 >= 64, no clamps
        int b  = blk / 31;
        int t0 = ((blk % 31) + 1) * TOK;
        run_block<false>(sm, b, t0, he, W1, W2, out);
    } else {                              // 16 blocks with t0 == 0 (clamped path)
        int b = blk - B_ * 31;
        run_block<true>(sm, b, 0, he, W1, W2, out);
    }
}

extern "C" void kernel_launch(void* const* d_in, const int* in_sizes, int n_in,
                              void* d_out, int out_size, void* d_ws, size_t ws_size,
                              hipStream_t stream) {
    const float* he = (const float*)d_in[0];
    const float* W1 = (const float*)d_in[1];
    const float* W2 = (const float*)d_in[2];
    float* out = (float*)d_out;
    // attention_len (d_in[3]) fixed at 48 (baked as A_)
    hipLaunchKernelGGL(ContextBlock_kernel, dim3(512), dim3(256), 0, stream, he, W1, W2, out);
}

// Round 11
// 120.640 us; speedup vs baseline: 1.0015x; 1.0015x over previous
//
#include <hip/hip_runtime.h>

// Problem constants (fixed by setup_inputs)
#define B_   16
#define T_   2048
#define F_   64
#define A_   48
#define TOK  64              // tokens per block (4 waves x 16 tokens)
#define WSTR 68              // fp32 window row stride (floats)
#define HWS  72              // f16 window row stride (halves): 144B, 16B-aligned rows
#define SSTR 49              // score row stride (floats)
#define NWIN 111             // window rows: t0-48 .. t0+62

typedef __attribute__((ext_vector_type(8))) _Float16 half8;  // 16x16x32 A/B frag
typedef __attribute__((ext_vector_type(4))) _Float16 half4;
typedef __attribute__((ext_vector_type(2))) _Float16 h2;
typedef __attribute__((ext_vector_type(4))) float    f32x4;  // 16x16x32 C/D frag

#define LOG2E 1.4426950408889634f

// Hardware-trans sigmoid (R3+R7: v_exp_f32+v_rcp_f32 beat any replacement).
// W pre-scaled by -log2e: sigma(x) = rcp(1 + 2^c).
__device__ __forceinline__ float sigp(float c) {
    return __builtin_amdgcn_rcpf(1.0f + __builtin_amdgcn_exp2f(c));
}
__device__ __forceinline__ h2 pk2(float a, float b) {
    return __builtin_bit_cast(h2, __builtin_amdgcn_cvt_pkrtz(a, b));
}
// K=32 frag from two C/D frags: elems 0..3 = sigma(a), 4..7 = sigma(b).
__device__ __forceinline__ half8 sig8(const f32x4& a, const f32x4& b) {
    h2 p0 = pk2(sigp(a[0]), sigp(a[1])), p1 = pk2(sigp(a[2]), sigp(a[3]));
    h2 p2 = pk2(sigp(b[0]), sigp(b[1])), p3 = pk2(sigp(b[2]), sigp(b[3]));
    half8 h;
    h[0]=p0[0]; h[1]=p0[1]; h[2]=p1[0]; h[3]=p1[1];
    h[4]=p2[0]; h[5]=p2[1]; h[6]=p3[0]; h[7]=p3[1];
    return h;
}

// Slot->semantic-feature map for all K=32 operands (layout-cancelling):
// F(kt,q,j) = 32kt + 16*(j>>2) + 4q + (j&3). A and B share the hardware
// (lane-group, elem)->k map, so packing BOTH sides by F makes the contraction
// sum over semantic features regardless of the actual hardware k layout.
// Compose identity: hb[kt] = sig8(c[2kt], c[2kt+1]).

// 4x2 MFMA sweep: c[mo] = A[mo][:] x hb (K=64 via 2 chained 16x16x32)
__device__ __forceinline__ void gemm42(const half8 (&aW)[4][2], const half8 (&hb)[2], f32x4 (&c)[4]) {
#pragma unroll
    for (int mo = 0; mo < 4; ++mo) {
        f32x4 z = {0.f, 0.f, 0.f, 0.f};
#pragma unroll
        for (int kt = 0; kt < 2; ++kt)
            z = __builtin_amdgcn_mfma_f32_16x16x32_f16(aW[mo][kt], hb[kt], z, 0, 0, 0);
        c[mo] = z;
    }
}

// Same 58.8 KB Smem as the 73.4us baseline. sWinH columns are PERMUTED
// (position p(f): chunk bits [b3 b2 b1 b0] -> [b3 b1 b0 b2]) so a b128 read
// at column kt*32+q*8 yields elems j holding feature F(kt,q,j).
struct Smem {
    float    sWin[NWIN * WSTR];    // 30.2 KB fp32 window, natural order (epilogue)
    _Float16 sWinH[NWIN * HWS];    // 16.0 KB f16 window, permuted columns (score B)
    float    sSc[TOK * SSTR];      // 12.5 KB scores
};

// FIRST = block contains tokens 0..63 (needs clamping + validity masks).
// R11: zero-wait main loop. The Y-sigmoid + score are DELAYED one step so
// every in-loop consumer reads values produced a full iteration earlier
// (c1, c2prev, gprev: all latency-retired). Each wave then issues its 64
// trans/step as a near-continuous stream -- if the 39% trans-pipe idle was
// dependency gaps (R10's collision theory, restated structurally), this
// recovers it; if the pipe is actually saturated, this is neutral and R9
// is the trans roofline.
template<bool FIRST>
__device__ __forceinline__ void run_block(Smem& sm, int b, int t0,
                                          const float* __restrict__ he,
                                          const float* __restrict__ W1,
                                          const float* __restrict__ W2,
                                          float* __restrict__ out)
{
    const int tid = threadIdx.x;
    const float* __restrict__ heB = he + (size_t)b * T_ * F_;

    // ---- stage window rows: fp32 natural + f16 permuted. g<0 rows never read.
    for (int i = tid; i < NWIN * 16; i += 256) {
        int row = i >> 4, ch = i & 15, c4 = ch * 4;
        int g = t0 - 48 + row;
        if (!FIRST || g >= 0) {
            float4 v = *(const float4*)(heB + (size_t)g * F_ + c4);
            *(float4*)(&sm.sWin[row * WSTR + c4]) = v;
            int cp = ((ch >> 3) << 3) | ((ch & 3) << 1) | ((ch >> 2) & 1);
            half4 h; h[0] = (_Float16)v.x; h[1] = (_Float16)v.y;
                     h[2] = (_Float16)v.z; h[3] = (_Float16)v.w;
            *(half4*)(&sm.sWinH[row * HWS + cp * 4]) = h;
        }
    }

    const int lane = tid & 63;
    const int wv   = tid >> 6;          // wave owns tokens wv*16 .. wv*16+15
    const int quad = lane >> 4;
    const int ml   = lane & 15;
    const int tw0  = wv * 16;
    const int tg   = t0 + tw0 + ml;     // this lane's token
    const int L    = min(A_, max(tg, 1));

    // ---- A-operands: A[mo][kt] elem j = -log2e * W[F(kt,q,j)][16mo+ml]
    half8 aW1[4][2], aW2[4][2];
    for (int mo = 0; mo < 4; ++mo)
        for (int kt = 0; kt < 2; ++kt) {
            half8 f1, f2;
#pragma unroll
            for (int j = 0; j < 8; ++j) {
                int fk = kt * 32 + ((j >> 2) << 4) + quad * 4 + (j & 3);
                f1[j] = (_Float16)(-LOG2E * W1[fk * F_ + mo * 16 + ml]);
                f2[j] = (_Float16)(-LOG2E * W2[fk * F_ + mo * 16 + ml]);
            }
            aW1[mo][kt] = f1; aW2[mo][kt] = f2;
        }

    // ---- initial H B-frags: hb[kt][j] = he[tg][F(kt,q,j)]
    half8 hb[2];
#pragma unroll
    for (int kt = 0; kt < 2; ++kt) {
        float4 vlo = *(const float4*)(heB + (size_t)tg * F_ + kt * 32 + quad * 4);
        float4 vhi = *(const float4*)(heB + (size_t)tg * F_ + kt * 32 + 16 + quad * 4);
        half8 h;
        h[0] = (_Float16)vlo.x; h[1] = (_Float16)vlo.y;
        h[2] = (_Float16)vlo.z; h[3] = (_Float16)vlo.w;
        h[4] = (_Float16)vhi.x; h[5] = (_Float16)vhi.y;
        h[6] = (_Float16)vhi.z; h[7] = (_Float16)vhi.w;
        hb[kt] = h;
    }

    // ---- prologue GEMM1 (register work overlaps the staging barrier)
    f32x4 c1[4];
    gemm42(aW1, hb, c1);

    __syncthreads();

    // Diag owner (C/D row = quad*4+reg, col = ml).
    const bool amDiag = (quad == (ml >> 2));
    const bool s0 = (ml & 3) == 0, s1 = (ml & 3) == 1, s2 = (ml & 3) == 2;
    float* scp = &sm.sSc[(tw0 + ml) * SSTR];

    // f16 window base (permuted cols): row for step a is tw0+ml+a.
    const _Float16* __restrict__ wbase = &sm.sWinH[(tw0 + ml) * HWS + quad * 8];

    auto wp_for = [&](int a2) -> const _Float16* {
        if (FIRST) {
            int j = tg - L + a2; if (j < 0) j = 0;
            return &sm.sWinH[(j + 48) * HWS + quad * 8];
        }
        return wbase + a2 * HWS;
    };

    // ---- peel a=0: sigma1, GEMMs, load g(0). No score yet.
    f32x4 c2p[4];
    half8 gp0, gp1;
    {
        hb[0] = sig8(c1[0], c1[1]);
        hb[1] = sig8(c1[2], c1[3]);
        gemm42(aW2, hb, c2p);
        gemm42(aW1, hb, c1);
        const _Float16* wp = wp_for(0);
        gp0 = *(const half8*)(wp);
        gp1 = *(const half8*)(wp + 32);
    }

    // ---- zero-wait main loop: a = 1..47; score for step a-1.
#pragma unroll 2
    for (int a = 1; a < A_; ++a) {
        // sigma1 of c1 (issued at iter a-1: retired)
        hb[0] = sig8(c1[0], c1[1]);
        hb[1] = sig8(c1[2], c1[3]);

        // issue this step's GEMM2 and next step's GEMM1 (results used at a+1)
        f32x4 c2n[4];
        gemm42(aW2, hb, c2n);
        gemm42(aW1, hb, c1);

        // sigma2 of c2prev (issued at iter a-1: retired)
        half8 y0 = sig8(c2p[0], c2p[1]);
        half8 y1 = sig8(c2p[2], c2p[3]);

        // score for step a-1 with g(a-1) (loaded at iter a-1: retired)
        f32x4 zs = {0.f, 0.f, 0.f, 0.f};
        zs = __builtin_amdgcn_mfma_f32_16x16x32_f16(y0, gp0, zs, 0, 0, 0);
        zs = __builtin_amdgcn_mfma_f32_16x16x32_f16(y1, gp1, zs, 0, 0, 0);
        float val = s0 ? zs[0] : (s1 ? zs[1] : (s2 ? zs[2] : zs[3]));
        if (FIRST) val = ((a - 1) < L) ? val : -1e9f;
        if (amDiag) scp[a - 1] = val;

        // load g(a) (consumed at iter a+1) and roll c2
        const _Float16* wp = wp_for(a);
        gp0 = *(const half8*)(wp);
        gp1 = *(const half8*)(wp + 32);
#pragma unroll
        for (int mo = 0; mo < 4; ++mo) c2p[mo] = c2n[mo];
    }

    // ---- epilogue: score for the final step A_-1
    {
        half8 y0 = sig8(c2p[0], c2p[1]);
        half8 y1 = sig8(c2p[2], c2p[3]);
        f32x4 zs = {0.f, 0.f, 0.f, 0.f};
        zs = __builtin_amdgcn_mfma_f32_16x16x32_f16(y0, gp0, zs, 0, 0, 0);
        zs = __builtin_amdgcn_mfma_f32_16x16x32_f16(y1, gp1, zs, 0, 0, 0);
        float val = s0 ? zs[0] : (s1 ? zs[1] : (s2 ? zs[2] : zs[3]));
        if (FIRST) val = ((A_ - 1) < L) ? val : -1e9f;
        if (amDiag) scp[A_ - 1] = val;
    }
    __syncthreads();

    // ---- softmax over a (48): 4 lanes per token, 12 scores each
    {
        int r = tid >> 2, s = tid & 3;
        float sc[12];
#pragma unroll
        for (int i = 0; i < 12; ++i) sc[i] = sm.sSc[r * SSTR + i * 4 + s];
        float m = sc[0];
#pragma unroll
        for (int i = 1; i < 12; ++i) m = fmaxf(m, sc[i]);
        m = fmaxf(m, __shfl_xor(m, 1));
        m = fmaxf(m, __shfl_xor(m, 2));
        float e[12]; float sum = 0.f;
#pragma unroll
        for (int i = 0; i < 12; ++i) { e[i] = __expf(sc[i] - m); sum += e[i]; }
        sum += __shfl_xor(sum, 1);
        sum += __shfl_xor(sum, 2);
        float inv = __builtin_amdgcn_rcpf(sum);
#pragma unroll
        for (int i = 0; i < 12; ++i) sm.sSc[r * SSTR + i * 4 + s] = e[i] * inv;
    }
    __syncthreads();

    // ---- ctx: 4 lanes per token, 16 features each (fp32 window, natural order)
    {
        int r = tid >> 2, fc = (tid & 3) * 16;
        int tgr = t0 + r;
        int Lr = min(A_, max(tgr, 1));
        float acc[16];
#pragma unroll
        for (int q = 0; q < 16; ++q) acc[q] = 0.f;
        for (int a = 0; a < A_; ++a) {
            float wgt = sm.sSc[r * SSTR + a];
            int j = tgr - Lr + a;
            if (FIRST) { if (j < 0) j = 0; }
            const float* wp = &sm.sWin[(j - t0 + 48) * WSTR + fc];
#pragma unroll
            for (int q = 0; q < 4; ++q) {
                float4 g = *(const float4*)(wp + q * 4);
                acc[q*4+0] += wgt * g.x; acc[q*4+1] += wgt * g.y;
                acc[q*4+2] += wgt * g.z; acc[q*4+3] += wgt * g.w;
            }
        }
        float* op = out + ((size_t)b * T_ + tgr) * F_ + fc;
#pragma unroll
        for (int q = 0; q < 4; ++q)
            *(float4*)(op + q * 4) = make_float4(acc[q*4], acc[q*4+1], acc[q*4+2], acc[q*4+3]);
    }
}

__global__ __launch_bounds__(256)
void ContextBlock_kernel(const float* __restrict__ he, const float* __restrict__ W1,
                         const float* __restrict__ W2, float* __restrict__ out)
{
    __shared__ Smem sm;                   // single 58.8 KB allocation, shared by both paths
    const int blk = blockIdx.x;
    if (blk < B_ * 31) {                  // 496 fast blocks: t0 >= 64, no clamps
        int b  = blk / 31;
        int t0 = ((blk % 31) + 1) * TOK;
        run_block<false>(sm, b, t0, he, W1, W2, out);
    } else {                              // 16 blocks with t0 == 0 (clamped path)
        int b = blk - B_ * 31;
        run_block<true>(sm, b, 0, he, W1, W2, out);
    }
}

extern "C" void kernel_launch(void* const* d_in, const int* in_sizes, int n_in,
                              void* d_out, int out_size, void* d_ws, size_t ws_size,
                              hipStream_t stream) {
    const float* he = (const float*)d_in[0];
    const float* W1 = (const float*)d_in[1];
    const float* W2 = (const float*)d_in[2];
    float* out = (float*)d_out;
    // attention_len (d_in[3]) fixed at 48 (baked as A_)
    hipLaunchKernelGGL(ContextBlock_kernel, dim3(512), dim3(256), 0, stream, he, W1, W2, out);
}